// Round 2
// baseline (378.123 us; speedup 1.0000x reference)
//
#include <hip/hip_runtime.h>

// Problem constants (from reference):
//   x:    (B=2, C=8, F=80, N=128, N=128) fp32
//   quad: (H=512, W=1024) int32 in [0, F)
//   uv:   (H, W, 2) fp32 in [0, N-1)
//   out:  (B, C, H, W) fp32
#define BC   16                 // B*C
#define FD   80
#define ND   128
#define NN   (ND * ND)          // 16384
#define HW   (512 * 1024)       // 524288 = 2^19
#define HW_SHIFT 19
#define CPT  8                  // channels per thread (BC/CPT thread-halves)

// Two-float pair with natural float alignment (4B) — legal at any texel
// address; compiler emits global_load_dwordx2 (gfx9+ supports dword-aligned
// 8B loads).
struct F2 { float a, b; };

__global__ __launch_bounds__(256)
void resample_uv_kernel(const float* __restrict__ x,
                        const int*   __restrict__ quad,
                        const float2* __restrict__ uv2,
                        float* __restrict__ out)
{
    const int gid  = blockIdx.x * 256 + threadIdx.x;   // half*HW + pix
    const int pix  = gid & (HW - 1);
    const int half = gid >> HW_SHIFT;                  // 0..1
    const int bc0  = half * CPT;

    // Per-pixel metadata (amortized over CPT channels).
    const float2 t = uv2[pix];
    const int    f = quad[pix];

    const float u = t.x;
    const float v = t.y;

    int u0 = (int)floorf(u);
    int v0 = (int)floorf(v);
    u0 = min(max(u0, 0), ND - 2);
    v0 = min(max(v0, 0), ND - 2);

    const float du = u - (float)u0;
    const float dv = v - (float)v0;

    const float w00 = (1.0f - du) * (1.0f - dv);
    const float w01 = du * (1.0f - dv);
    const float w10 = (1.0f - du) * dv;
    const float w11 = du * dv;

    // Base texel address for channel bc0; channels stride by FD*NN floats.
    const float* base = x + ((size_t)bc0 * FD + (size_t)f) * NN
                          + (size_t)(v0 * ND + u0);

    // Issue all 2*CPT paired loads before consuming any — max MLP.
    F2 r0[CPT], r1[CPT];
#pragma unroll
    for (int c = 0; c < CPT; ++c) {
        const float* p = base + (size_t)c * (FD * NN);
        r0[c] = *(const F2*)(p);
        r1[c] = *(const F2*)(p + ND);
    }

    // Blend + streaming store (bypass L2 to keep texture resident).
#pragma unroll
    for (int c = 0; c < CPT; ++c) {
        const float val = r0[c].a * w00 + r0[c].b * w01
                        + r1[c].a * w10 + r1[c].b * w11;
        __builtin_nontemporal_store(val, &out[(size_t)(bc0 + c) * HW + pix]);
    }
}

extern "C" void kernel_launch(void* const* d_in, const int* in_sizes, int n_in,
                              void* d_out, int out_size, void* d_ws, size_t ws_size,
                              hipStream_t stream)
{
    const float*  x    = (const float*)d_in[0];
    const int*    quad = (const int*)d_in[1];
    const float2* uv2  = (const float2*)d_in[2];
    float*        out  = (float*)d_out;

    const int total = (BC / CPT) * HW;           // 1,048,576 threads
    const int block = 256;
    const int grid  = total / block;             // 4096 blocks

    resample_uv_kernel<<<grid, block, 0, stream>>>(x, quad, uv2, out);
}

// Round 3
// 179.568 us; speedup vs baseline: 2.1057x; 2.1057x over previous
//
#include <hip/hip_runtime.h>

// Problem constants (from reference):
//   x:    (B=2, C=8, F=80, N=128, N=128) fp32
//   quad: (H=512, W=1024) int32 in [0, F)
//   uv:   (H, W, 2) fp32 in [0, N-1)
//   out:  (B, C, H, W) fp32
#define BC   16                 // B*C
#define FD   80
#define ND   128
#define NN   (ND * ND)          // 16384
#define HW   (512 * 1024)       // 524288 = 2^19
#define HW_SHIFT 19

#define Y_BYTES ((size_t)FD * NN * BC * sizeof(float))   // 83,886,080

// ---------------------------------------------------------------------------
// Kernel 1: repack x[bc][f][v][u] -> y[f][v][u][bc]  (channels innermost).
// One block per (f, v) row: 128 u-values x 16 channels = 2048 floats.
// Reads coalesced along u; writes fully coalesced (flat consecutive).
// ---------------------------------------------------------------------------
__global__ __launch_bounds__(256)
void repack_kernel(const float* __restrict__ x, float* __restrict__ y)
{
    const int fv = blockIdx.x;           // 0 .. FD*ND-1
    const int f  = fv / ND;
    const int v  = fv - f * ND;
    const int tid = threadIdx.x;

    __shared__ float lds[ND * 17];       // stride 17 breaks bank conflicts

    // Phase 1: load 16 channels x 128 u, coalesced along u.
#pragma unroll
    for (int i = tid; i < BC * ND; i += 256) {
        const int bc = i >> 7;           // i / 128
        const int u  = i & (ND - 1);
        lds[u * 17 + bc] = x[(((size_t)bc * FD + f) * ND + v) * ND + u];
    }
    __syncthreads();

    // Phase 2: write y[f][v][u][bc] as float4 (flat consecutive -> coalesced).
    float4* y4 = (float4*)(y + (size_t)fv * ND * BC);
#pragma unroll
    for (int k = tid; k < (BC * ND) / 4; k += 256) {   // 512 float4
        const int u  = k >> 2;
        const int c0 = (k & 3) * 4;
        float4 r;
        r.x = lds[u * 17 + c0 + 0];
        r.y = lds[u * 17 + c0 + 1];
        r.z = lds[u * 17 + c0 + 2];
        r.w = lds[u * 17 + c0 + 3];
        y4[k] = r;
    }
}

// ---------------------------------------------------------------------------
// Kernel 2: gather. 4 lanes per pixel, 4 channels per lane.
// The 4 lanes of a pixel read 4 consecutive float4s of the same 64B line,
// so the coalescer issues exactly one line fetch per texel position.
// ---------------------------------------------------------------------------
__global__ __launch_bounds__(256)
void gather_kernel(const float* __restrict__ y,
                   const int*   __restrict__ quad,
                   const float2* __restrict__ uv2,
                   float* __restrict__ out)
{
    const int gid = blockIdx.x * 256 + threadIdx.x;
    const int pix = gid >> 2;
    const int bc0 = (gid & 3) * 4;

    const float2 t = uv2[pix];   // 4 lanes same addr -> broadcast
    const int    f = quad[pix];

    const float u = t.x;
    const float v = t.y;

    int u0 = (int)floorf(u);
    int v0 = (int)floorf(v);
    u0 = min(max(u0, 0), ND - 2);
    v0 = min(max(v0, 0), ND - 2);

    const float du = u - (float)u0;
    const float dv = v - (float)v0;

    const float w00 = (1.0f - du) * (1.0f - dv);
    const float w01 = du * (1.0f - dv);
    const float w10 = (1.0f - du) * dv;
    const float w11 = du * dv;

    const size_t base = (((size_t)f * ND + v0) * ND + u0) * BC + bc0;
    const float4 g00 = *(const float4*)(y + base);
    const float4 g01 = *(const float4*)(y + base + BC);
    const float4 g10 = *(const float4*)(y + base + (size_t)ND * BC);
    const float4 g11 = *(const float4*)(y + base + (size_t)ND * BC + BC);

    const float o0 = g00.x * w00 + g01.x * w01 + g10.x * w10 + g11.x * w11;
    const float o1 = g00.y * w00 + g01.y * w01 + g10.y * w10 + g11.y * w11;
    const float o2 = g00.z * w00 + g01.z * w01 + g10.z * w10 + g11.z * w11;
    const float o3 = g00.w * w00 + g01.w * w01 + g10.w * w10 + g11.w * w11;

    __builtin_nontemporal_store(o0, &out[(size_t)(bc0 + 0) * HW + pix]);
    __builtin_nontemporal_store(o1, &out[(size_t)(bc0 + 1) * HW + pix]);
    __builtin_nontemporal_store(o2, &out[(size_t)(bc0 + 2) * HW + pix]);
    __builtin_nontemporal_store(o3, &out[(size_t)(bc0 + 3) * HW + pix]);
}

// ---------------------------------------------------------------------------
// Fallback (round-1 kernel): used only if ws_size can't hold the repacked
// texture. One thread per output element, scalar gathers.
// ---------------------------------------------------------------------------
__global__ __launch_bounds__(256)
void resample_fallback_kernel(const float* __restrict__ x,
                              const int*   __restrict__ quad,
                              const float2* __restrict__ uv2,
                              float* __restrict__ out)
{
    const int gid = blockIdx.x * 256 + threadIdx.x;
    const int pix = gid & (HW - 1);
    const int bc  = gid >> HW_SHIFT;

    const float2 t = uv2[pix];
    const int    f = quad[pix];

    const float u = t.x;
    const float v = t.y;

    int u0 = (int)floorf(u);
    int v0 = (int)floorf(v);
    u0 = min(max(u0, 0), ND - 2);
    v0 = min(max(v0, 0), ND - 2);

    const float du = u - (float)u0;
    const float dv = v - (float)v0;

    const float w00 = (1.0f - du) * (1.0f - dv);
    const float w01 = du * (1.0f - dv);
    const float w10 = (1.0f - du) * dv;
    const float w11 = du * dv;

    const float* p = x + ((size_t)bc * FD + (size_t)f) * NN + v0 * ND + u0;
    out[gid] = p[0] * w00 + p[1] * w01 + p[ND] * w10 + p[ND + 1] * w11;
}

extern "C" void kernel_launch(void* const* d_in, const int* in_sizes, int n_in,
                              void* d_out, int out_size, void* d_ws, size_t ws_size,
                              hipStream_t stream)
{
    const float*  x    = (const float*)d_in[0];
    const int*    quad = (const int*)d_in[1];
    const float2* uv2  = (const float2*)d_in[2];
    float*        out  = (float*)d_out;

    if (ws_size >= Y_BYTES) {
        float* y = (float*)d_ws;
        repack_kernel<<<FD * ND, 256, 0, stream>>>(x, y);          // 10240 blocks
        const int total = 4 * HW;                                  // 2,097,152
        gather_kernel<<<total / 256, 256, 0, stream>>>(y, quad, uv2, out);
    } else {
        const int total = BC * HW;
        resample_fallback_kernel<<<total / 256, 256, 0, stream>>>(x, quad, uv2, out);
    }
}

// Round 4
// 169.974 us; speedup vs baseline: 2.2246x; 1.0564x over previous
//
#include <hip/hip_runtime.h>
#include <hip/hip_fp16.h>

// Problem constants (from reference):
//   x:    (B=2, C=8, F=80, N=128, N=128) fp32
//   quad: (H=512, W=1024) int32 in [0, F)
//   uv:   (H, W, 2) fp32 in [0, N-1)
//   out:  (B, C, H, W) fp32
#define BC   16                 // B*C
#define FD   80
#define ND   128
#define NN   (ND * ND)          // 16384
#define HW   (512 * 1024)       // 524288 = 2^19
#define HW_SHIFT 19

#define YH_BYTES ((size_t)FD * NN * BC * sizeof(__half))   // 41,943,040

// ---------------------------------------------------------------------------
// Kernel 1: repack x[bc][f][v][u] (fp32) -> y[f][v][u][bc] (fp16, channels
// innermost). One block per (f, v) row: 128 u x 16 ch = 2048 values.
// Reads coalesced along u; writes 4 KB contiguous per block as uint4.
// ---------------------------------------------------------------------------
__global__ __launch_bounds__(256)
void repack_kernel(const float* __restrict__ x, __half* __restrict__ y)
{
    const int fv = blockIdx.x;           // 0 .. FD*ND-1
    const int f  = fv / ND;
    const int v  = fv - f * ND;
    const int tid = threadIdx.x;

    __shared__ float lds[ND * 17];       // stride 17 breaks bank conflicts

#pragma unroll
    for (int i = tid; i < BC * ND; i += 256) {
        const int bc = i >> 7;           // i / 128
        const int u  = i & (ND - 1);
        lds[u * 17 + bc] = x[(((size_t)bc * FD + f) * ND + v) * ND + u];
    }
    __syncthreads();

    // Each thread packs 8 consecutive halves (16 B): u = tid>>1, c0 = (tid&1)*8.
    const int u  = tid >> 1;
    const int c0 = (tid & 1) * 8;
    uint4 r;
    unsigned* rp = (unsigned*)&r;
#pragma unroll
    for (int j = 0; j < 4; ++j) {
        const __half2 h = __floats2half2_rn(lds[u * 17 + c0 + 2 * j],
                                            lds[u * 17 + c0 + 2 * j + 1]);
        rp[j] = *(const unsigned*)&h;
    }
    uint4* y4 = (uint4*)(y + (size_t)fv * ND * BC);
    y4[tid] = r;                         // byte off = u*32 + c0*2, 16B aligned
}

// ---------------------------------------------------------------------------
// Kernel 2: gather. 4 lanes per pixel, 4 channels per lane (8 B fp16 loads).
// The 4 lanes of a pixel cover one 32 B span; both u-positions of a v-row
// are 64 B contiguous, so the coalescer fetches ~1 line per row.
// ---------------------------------------------------------------------------
__device__ inline float4 loadh4(const __half* p)
{
    const __half2* q = (const __half2*)p;   // 8B-aligned (bc0 multiple of 4)
    const float2 fa = __half22float2(q[0]);
    const float2 fb = __half22float2(q[1]);
    return make_float4(fa.x, fa.y, fb.x, fb.y);
}

__global__ __launch_bounds__(256)
void gather_kernel(const __half* __restrict__ y,
                   const int*    __restrict__ quad,
                   const float2* __restrict__ uv2,
                   float* __restrict__ out)
{
    const int gid = blockIdx.x * 256 + threadIdx.x;
    const int pix = gid >> 2;
    const int bc0 = (gid & 3) * 4;

    const float2 t = uv2[pix];   // 4 lanes same addr -> broadcast
    const int    f = quad[pix];

    const float u = t.x;
    const float v = t.y;

    int u0 = (int)floorf(u);
    int v0 = (int)floorf(v);
    u0 = min(max(u0, 0), ND - 2);
    v0 = min(max(v0, 0), ND - 2);

    const float du = u - (float)u0;
    const float dv = v - (float)v0;

    const float w00 = (1.0f - du) * (1.0f - dv);
    const float w01 = du * (1.0f - dv);
    const float w10 = (1.0f - du) * dv;
    const float w11 = du * dv;

    const size_t base = (((size_t)f * ND + v0) * ND + u0) * BC + bc0;
    const float4 g00 = loadh4(y + base);
    const float4 g01 = loadh4(y + base + BC);
    const float4 g10 = loadh4(y + base + (size_t)ND * BC);
    const float4 g11 = loadh4(y + base + (size_t)ND * BC + BC);

    const float o0 = g00.x * w00 + g01.x * w01 + g10.x * w10 + g11.x * w11;
    const float o1 = g00.y * w00 + g01.y * w01 + g10.y * w10 + g11.y * w11;
    const float o2 = g00.z * w00 + g01.z * w01 + g10.z * w10 + g11.z * w11;
    const float o3 = g00.w * w00 + g01.w * w01 + g10.w * w10 + g11.w * w11;

    __builtin_nontemporal_store(o0, &out[(size_t)(bc0 + 0) * HW + pix]);
    __builtin_nontemporal_store(o1, &out[(size_t)(bc0 + 1) * HW + pix]);
    __builtin_nontemporal_store(o2, &out[(size_t)(bc0 + 2) * HW + pix]);
    __builtin_nontemporal_store(o3, &out[(size_t)(bc0 + 3) * HW + pix]);
}

// ---------------------------------------------------------------------------
// Fallback (round-1 kernel): used only if ws_size can't hold the repacked
// texture. One thread per output element, scalar fp32 gathers.
// ---------------------------------------------------------------------------
__global__ __launch_bounds__(256)
void resample_fallback_kernel(const float* __restrict__ x,
                              const int*   __restrict__ quad,
                              const float2* __restrict__ uv2,
                              float* __restrict__ out)
{
    const int gid = blockIdx.x * 256 + threadIdx.x;
    const int pix = gid & (HW - 1);
    const int bc  = gid >> HW_SHIFT;

    const float2 t = uv2[pix];
    const int    f = quad[pix];

    const float u = t.x;
    const float v = t.y;

    int u0 = (int)floorf(u);
    int v0 = (int)floorf(v);
    u0 = min(max(u0, 0), ND - 2);
    v0 = min(max(v0, 0), ND - 2);

    const float du = u - (float)u0;
    const float dv = v - (float)v0;

    const float w00 = (1.0f - du) * (1.0f - dv);
    const float w01 = du * (1.0f - dv);
    const float w10 = (1.0f - du) * dv;
    const float w11 = du * dv;

    const float* p = x + ((size_t)bc * FD + (size_t)f) * NN + v0 * ND + u0;
    out[gid] = p[0] * w00 + p[1] * w01 + p[ND] * w10 + p[ND + 1] * w11;
}

extern "C" void kernel_launch(void* const* d_in, const int* in_sizes, int n_in,
                              void* d_out, int out_size, void* d_ws, size_t ws_size,
                              hipStream_t stream)
{
    const float*  x    = (const float*)d_in[0];
    const int*    quad = (const int*)d_in[1];
    const float2* uv2  = (const float2*)d_in[2];
    float*        out  = (float*)d_out;

    if (ws_size >= YH_BYTES) {
        __half* y = (__half*)d_ws;
        repack_kernel<<<FD * ND, 256, 0, stream>>>(x, y);          // 10240 blocks
        const int total = 4 * HW;                                  // 2,097,152
        gather_kernel<<<total / 256, 256, 0, stream>>>(y, quad, uv2, out);
    } else {
        const int total = BC * HW;
        resample_fallback_kernel<<<total / 256, 256, 0, stream>>>(x, quad, uv2, out);
    }
}

// Round 5
// 167.154 us; speedup vs baseline: 2.2621x; 1.0169x over previous
//
#include <hip/hip_runtime.h>
#include <hip/hip_fp16.h>

// Problem constants (from reference):
//   x:    (B=2, C=8, F=80, N=128, N=128) fp32
//   quad: (H=512, W=1024) int32 in [0, F)
//   uv:   (H, W, 2) fp32 in [0, N-1)
//   out:  (B, C, H, W) fp32
#define BC   16                 // B*C
#define FD   80
#define ND   128
#define NN   (ND * ND)          // 16384
#define HW   (512 * 1024)       // 524288 = 2^19
#define HW_SHIFT 19

#define YH_BYTES ((size_t)FD * NN * BC * sizeof(__half))   // 41,943,040

// ---------------------------------------------------------------------------
// Kernel 1: repack x[bc][f][v][u] (fp32) -> y[f][v][u][bc] (fp16, channels
// innermost). One block per (f, v) row: 128 u x 16 ch = 2048 values.
// v2: float4 global loads (3 VMEM per thread total) + LDS transpose.
// ---------------------------------------------------------------------------
__global__ __launch_bounds__(256)
void repack_kernel(const float* __restrict__ x, __half* __restrict__ y)
{
    const int fv  = blockIdx.x;          // 0 .. FD*ND-1
    const int f   = fv >> 7;             // fv / ND
    const int v   = fv & (ND - 1);
    const int tid = threadIdx.x;

    __shared__ float lds[ND * 17];       // stride 17 breaks bank conflicts

    // Phase 1: 512 float4 loads cover 16 ch x 128 u; coalesced along u.
#pragma unroll
    for (int r = 0; r < 2; ++r) {
        const int i4 = tid + r * 256;    // 0..511
        const int c  = i4 >> 5;          // 0..15
        const int u4 = i4 & 31;          // 0..31 (float4 index along u)
        const float4 val = *(const float4*)(
            x + (((size_t)c * FD + f) * ND + v) * ND + u4 * 4);
        lds[(u4 * 4 + 0) * 17 + c] = val.x;
        lds[(u4 * 4 + 1) * 17 + c] = val.y;
        lds[(u4 * 4 + 2) * 17 + c] = val.z;
        lds[(u4 * 4 + 3) * 17 + c] = val.w;
    }
    __syncthreads();

    // Phase 2: each thread packs 8 consecutive halves (16 B).
    const int u  = tid >> 1;
    const int c0 = (tid & 1) * 8;
    uint4 r;
    unsigned* rp = (unsigned*)&r;
#pragma unroll
    for (int j = 0; j < 4; ++j) {
        const __half2 h = __floats2half2_rn(lds[u * 17 + c0 + 2 * j],
                                            lds[u * 17 + c0 + 2 * j + 1]);
        rp[j] = *(const unsigned*)&h;
    }
    uint4* y4 = (uint4*)(y + (size_t)fv * ND * BC);
    y4[tid] = r;                         // 4 KB contiguous per block
}

// ---------------------------------------------------------------------------
// Kernel 2: gather. v2: ONE thread per pixel, all 16 channels.
// Per pixel: 2 metadata loads, 8 uint4 texel loads (the 64B v-row span
// (u0,u0+1)x16ch is fully consumed), 16 coalesced scalar stores.
// ---------------------------------------------------------------------------
__device__ inline void acc8(float* o, uint4 t, float w)
{
    const unsigned* p = (const unsigned*)&t;
#pragma unroll
    for (int j = 0; j < 4; ++j) {
        const float2 fp = __half22float2(*(const __half2*)&p[j]);
        o[2 * j + 0] += fp.x * w;
        o[2 * j + 1] += fp.y * w;
    }
}

__global__ __launch_bounds__(256)
void gather_kernel(const __half* __restrict__ y,
                   const int*    __restrict__ quad,
                   const float2* __restrict__ uv2,
                   float* __restrict__ out)
{
    const int pix = blockIdx.x * 256 + threadIdx.x;

    const float2 t = uv2[pix];
    const int    f = quad[pix];

    const float u = t.x;
    const float v = t.y;

    int u0 = (int)floorf(u);
    int v0 = (int)floorf(v);
    u0 = min(max(u0, 0), ND - 2);
    v0 = min(max(v0, 0), ND - 2);

    // Issue all 8 texel loads (128 B, all consumed) before the weight math.
    const size_t base = (((size_t)f * ND + v0) * ND + u0) * BC;
    const uint4* r0 = (const uint4*)(y + base);                    // (v0,  u0..u0+1)
    const uint4* r1 = (const uint4*)(y + base + (size_t)ND * BC);  // (v0+1,u0..u0+1)
    const uint4 a0 = r0[0], a1 = r0[1];   // (v0,u0)   ch0-7, ch8-15
    const uint4 b0 = r0[2], b1 = r0[3];   // (v0,u0+1)
    const uint4 c0 = r1[0], c1 = r1[1];   // (v1,u0)
    const uint4 d0 = r1[2], d1 = r1[3];   // (v1,u0+1)

    const float du = u - (float)u0;
    const float dv = v - (float)v0;
    const float w00 = (1.0f - du) * (1.0f - dv);
    const float w01 = du * (1.0f - dv);
    const float w10 = (1.0f - du) * dv;
    const float w11 = du * dv;

    float o[BC];
#pragma unroll
    for (int c = 0; c < BC; ++c) o[c] = 0.0f;

    acc8(o,     a0, w00); acc8(o + 8, a1, w00);
    acc8(o,     b0, w01); acc8(o + 8, b1, w01);
    acc8(o,     c0, w10); acc8(o + 8, c1, w10);
    acc8(o,     d0, w11); acc8(o + 8, d1, w11);

    // 16 coalesced scalar stores (64 consecutive pixels per wave per plane).
#pragma unroll
    for (int c = 0; c < BC; ++c)
        __builtin_nontemporal_store(o[c], &out[(size_t)c * HW + pix]);
}

// ---------------------------------------------------------------------------
// Fallback: used only if ws_size can't hold the repacked texture.
// ---------------------------------------------------------------------------
__global__ __launch_bounds__(256)
void resample_fallback_kernel(const float* __restrict__ x,
                              const int*   __restrict__ quad,
                              const float2* __restrict__ uv2,
                              float* __restrict__ out)
{
    const int gid = blockIdx.x * 256 + threadIdx.x;
    const int pix = gid & (HW - 1);
    const int bc  = gid >> HW_SHIFT;

    const float2 t = uv2[pix];
    const int    f = quad[pix];

    const float u = t.x;
    const float v = t.y;

    int u0 = (int)floorf(u);
    int v0 = (int)floorf(v);
    u0 = min(max(u0, 0), ND - 2);
    v0 = min(max(v0, 0), ND - 2);

    const float du = u - (float)u0;
    const float dv = v - (float)v0;

    const float w00 = (1.0f - du) * (1.0f - dv);
    const float w01 = du * (1.0f - dv);
    const float w10 = (1.0f - du) * dv;
    const float w11 = du * dv;

    const float* p = x + ((size_t)bc * FD + (size_t)f) * NN + v0 * ND + u0;
    out[gid] = p[0] * w00 + p[1] * w01 + p[ND] * w10 + p[ND + 1] * w11;
}

extern "C" void kernel_launch(void* const* d_in, const int* in_sizes, int n_in,
                              void* d_out, int out_size, void* d_ws, size_t ws_size,
                              hipStream_t stream)
{
    const float*  x    = (const float*)d_in[0];
    const int*    quad = (const int*)d_in[1];
    const float2* uv2  = (const float2*)d_in[2];
    float*        out  = (float*)d_out;

    if (ws_size >= YH_BYTES) {
        __half* y = (__half*)d_ws;
        repack_kernel<<<FD * ND, 256, 0, stream>>>(x, y);      // 10240 blocks
        gather_kernel<<<HW / 256, 256, 0, stream>>>(y, quad, uv2, out);  // 2048 blocks
    } else {
        const int total = BC * HW;
        resample_fallback_kernel<<<total / 256, 256, 0, stream>>>(x, quad, uv2, out);
    }
}